// Round 4
// baseline (452.677 us; speedup 1.0000x reference)
//
#include <hip/hip_runtime.h>

// ---------------------------------------------------------------------------
// 2-layer GCN on MI355X.
//   h   = relu( Dinv (A+I) Dinv (z @ W1) + b1 )
//   out =       Dinv (A+I) Dinv (h @ W2) + b2
// R13: XCD column-sliced aggregation, lean inner loop.
// R12 evidence: chunk-major 32-col slices + blockIdx%8 pinning DID make
// gathers L2-resident (FETCH 188->57 MB) but per-node-visit overhead
// (12-shfl butterfly + serial 8-node r-loop, x8 chunk passes) made it
// instruction-bound (164us, VALU 48%, HBM 6.6%). R13 restructure:
// one wave = 16 node-groups x 4 lanes; each group owns ONE node's 32-col
// chunk (16B/lane) and walks its own CSR row. Lane-local accumulation ->
// NO shfl, no serial epilogue; one gather instr = 16 edges x 64B = 1KB.
// Divergence (groups run to max degree in wave) is exec-masked. Unroll-2
// with two acc banks for 2-deep MLP per group.
// 8 dispatches: memset, prep, scan, fill, gemm1, agg1, gemm2, agg2.
// ---------------------------------------------------------------------------

#define N_NODES 50000
#define N_EDGES 800000
#define D_IN    256
#define D_HID   256
#define D_OUT   128

typedef unsigned int uint32;
typedef unsigned short u16;

typedef __attribute__((ext_vector_type(8))) short bf16x8;   // MFMA A/B frag
typedef __attribute__((ext_vector_type(4))) float f32x4;    // MFMA C/D frag

__device__ __forceinline__ u16 f2bf_rne(float f) {
    union { float f; uint32 u; } c; c.f = f;
    uint32 u = c.u;
    u += 0x7FFFu + ((u >> 16) & 1u);
    return (u16)(u >> 16);
}
__device__ __forceinline__ float bf_lo(uint32 p) {
    union { uint32 u; float f; } c; c.u = p << 16; return c.f;
}
__device__ __forceinline__ float bf_hi(uint32 p) {
    union { uint32 u; float f; } c; c.u = p & 0xFFFF0000u; return c.f;
}

// ---------------- fused independent prep ----------------
// z->bf16, W1^T bf16, W2^T bf16, degree atomics WITH rank capture.

__global__ __launch_bounds__(256) void prep_kernel(const float* __restrict__ z,
                                                   const int* __restrict__ dst,
                                                   const float* __restrict__ W1,
                                                   const float* __restrict__ W2,
                                                   u16* __restrict__ zb,
                                                   u16* __restrict__ w1t,
                                                   u16* __restrict__ w2t,
                                                   int* __restrict__ cnt,
                                                   int* __restrict__ rank) {
    const int g = blockIdx.x * 256 + threadIdx.x;
    const int GT = gridDim.x * 256;

    for (int c = g; c < N_NODES * D_IN / 8; c += GT) {
        int i = c * 8;
        float4 a = *(const float4*)(z + i);
        float4 d = *(const float4*)(z + i + 4);
        uint4 pk;
        pk.x = (uint32)f2bf_rne(a.x) | ((uint32)f2bf_rne(a.y) << 16);
        pk.y = (uint32)f2bf_rne(a.z) | ((uint32)f2bf_rne(a.w) << 16);
        pk.z = (uint32)f2bf_rne(d.x) | ((uint32)f2bf_rne(d.y) << 16);
        pk.w = (uint32)f2bf_rne(d.z) | ((uint32)f2bf_rne(d.w) << 16);
        *(uint4*)(zb + i) = pk;
    }
    for (int idx = g; idx < D_IN * D_HID + D_HID * D_OUT; idx += GT) {
        if (idx < D_IN * D_HID) {
            int nrow = idx >> 8, kcol = idx & 255;
            w1t[idx] = f2bf_rne(W1[kcol * D_HID + nrow]);
        } else {
            int j = idx - D_IN * D_HID;
            int nrow = j >> 8, kcol = j & 255;
            w2t[j] = f2bf_rne(W2[kcol * D_OUT + nrow]);
        }
    }
    for (int i = g; i < N_EDGES; i += GT)
        rank[i] = atomicAdd(&cnt[dst[i]], 1);
}

// ---------------- single-block vectorized scan ----------------

__global__ __launch_bounds__(1024) void scan_kernel(const int* __restrict__ cnt,
                                                    float* __restrict__ dinv,
                                                    int* __restrict__ row_ptr, int n) {
    __shared__ int wtot[16];
    __shared__ int carry_s;
    const int t = threadIdx.x;
    const int lane = t & 63, w = t >> 6;
    if (t == 0) carry_s = 0;
    __syncthreads();

    const int n4 = n >> 2;
    for (int base = 0; base < n4; base += 1024) {
        int i4 = base + t;
        int4 v = make_int4(0, 0, 0, 0);
        if (i4 < n4) v = ((const int4*)cnt)[i4];
        int s = v.x + v.y + v.z + v.w;
        int x = s;
        #pragma unroll
        for (int off = 1; off < 64; off <<= 1) {
            int u = __shfl_up(x, off, 64);
            if (lane >= off) x += u;
        }
        if (lane == 63) wtot[w] = x;
        __syncthreads();

        int wbase = 0;
        #pragma unroll
        for (int j = 0; j < 16; ++j) if (j < w) wbase += wtot[j];
        int excl = carry_s + wbase + x - s;
        if (i4 < n4) {
            int4 rp;
            rp.x = excl;
            rp.y = rp.x + v.x;
            rp.z = rp.y + v.y;
            rp.w = rp.z + v.z;
            ((int4*)row_ptr)[i4] = rp;
            float4 dv;
            dv.x = rsqrtf((float)(v.x + 1));
            dv.y = rsqrtf((float)(v.y + 1));
            dv.z = rsqrtf((float)(v.z + 1));
            dv.w = rsqrtf((float)(v.w + 1));
            ((float4*)dinv)[i4] = dv;
        }
        __syncthreads();
        if (t == 0) {
            int tot = 0;
            #pragma unroll
            for (int j = 0; j < 16; ++j) tot += wtot[j];
            carry_s += tot;
        }
        __syncthreads();
    }
    if (t == 0) row_ptr[n] = carry_s;
}

// ---------------- atomic-free CSR fill: packed (col, weight) ----------------

__global__ void fill_kernel(const int* __restrict__ src, const int* __restrict__ dst,
                            const int* __restrict__ rank, const int* __restrict__ row_ptr,
                            const float* __restrict__ dinv,
                            int2* __restrict__ edata, int n_edges) {
    int i = blockIdx.x * blockDim.x + threadIdx.x;
    if (i < n_edges) {
        int s = src[i], d = dst[i];
        float w = dinv[s] * dinv[d];
        edata[row_ptr[d] + rank[i]] = make_int2(s, __float_as_int(w));
    }
}

// ---------------- bf16 MFMA GEMM (C chunk-major; A row- or chunk-major) ----

template <int NT, bool ACH>
__global__ __launch_bounds__(256, 4) void gemm_bf16_kernel(const u16* __restrict__ A,
                                                           const u16* __restrict__ BT,
                                                           u16* __restrict__ C, int M) {
    const int K = 256;
    __shared__ short As[128 * 32];
    __shared__ short Bs[128 * 32];

    const int m0 = blockIdx.x * 128;
    const int n0 = blockIdx.y * 128;
    const int t  = threadIdx.x;
    const int w  = t >> 6;
    const int lane = t & 63;
    const int lm = lane & 15;
    const int lq = lane >> 4;
    const int wm = w & 1;
    const int wn = w >> 1;

    f32x4 acc[4][4] = {};

    for (int k0 = 0; k0 < K; k0 += 32) {
        #pragma unroll
        for (int j = 0; j < 2; ++j) {
            int c = w * 128 + j * 64 + lane;
            int row = c >> 2;
            int kc = k0 + (c & 3) * 8;
            int gm = m0 + row; if (gm >= M) gm = M - 1;
            const u16* gpa;
            if constexpr (ACH)
                gpa = A + (size_t)(kc >> 5) * (size_t)M * 32 + (size_t)gm * 32 + (kc & 31);
            else
                gpa = A + (size_t)gm * K + kc;
            const u16* gpb = BT + (size_t)(n0 + row) * K + kc;
            __builtin_amdgcn_global_load_lds(
                (const __attribute__((address_space(1))) void*)gpa,
                (__attribute__((address_space(3))) void*)(As + (w * 128 + j * 64) * 8),
                16, 0, 0);
            __builtin_amdgcn_global_load_lds(
                (const __attribute__((address_space(1))) void*)gpb,
                (__attribute__((address_space(3))) void*)(Bs + (w * 128 + j * 64) * 8),
                16, 0, 0);
        }
        __syncthreads();

        bf16x8 af[4], bf[4];
        #pragma unroll
        for (int mt = 0; mt < 4; ++mt)
            af[mt] = *(const bf16x8*)&As[(wm * 64 + mt * 16 + lm) * 32 + lq * 8];
        #pragma unroll
        for (int nt = 0; nt < 4; ++nt)
            bf[nt] = *(const bf16x8*)&Bs[(wn * 64 + nt * 16 + lm) * 32 + lq * 8];

        #pragma unroll
        for (int mt = 0; mt < 4; ++mt)
            #pragma unroll
            for (int nt = 0; nt < 4; ++nt)
                acc[mt][nt] = __builtin_amdgcn_mfma_f32_16x16x32_bf16(
                    af[mt], bf[nt], acc[mt][nt], 0, 0, 0);

        __syncthreads();
    }

    // C write: chunk-major [gn>>5][gm][gn&31]
    #pragma unroll
    for (int mt = 0; mt < 4; ++mt) {
        #pragma unroll
        for (int r = 0; r < 4; ++r) {
            int gm = m0 + wm * 64 + mt * 16 + lq * 4 + r;
            if (gm < M) {
                #pragma unroll
                for (int nt = 0; nt < 4; ++nt) {
                    int gn = n0 + wn * 64 + nt * 16 + lm;
                    C[(size_t)(gn >> 5) * (size_t)M * 32 + (size_t)gm * 32 + (gn & 31)]
                        = f2bf_rne(acc[mt][nt][r]);
                }
            }
        }
    }
}

// ---------------- XCD column-sliced aggregation, group-per-node ------------
// chunk = blockIdx%8 (mod NCH): each XCD works one 32-col chunk whose
// [n_nodes x 32] bf16 slice (3.2/1.6 MB) is contiguous and L2-resident
// (verified R12: FETCH 188->57MB). One wave = 16 groups x 4 lanes; group g
// owns node nb+g's chunk row (16B/lane) and walks its own CSR row. Pure
// lane-local accumulation: no shfl, no cross-lane epilogue. One gather
// instruction = 16 independent edges x 64B. Expired groups are exec-masked.

__device__ __forceinline__ void upd8(float* a, uint4 p, float w) {
    a[0] = fmaf(bf_lo(p.x), w, a[0]);
    a[1] = fmaf(bf_hi(p.x), w, a[1]);
    a[2] = fmaf(bf_lo(p.y), w, a[2]);
    a[3] = fmaf(bf_hi(p.y), w, a[3]);
    a[4] = fmaf(bf_lo(p.z), w, a[4]);
    a[5] = fmaf(bf_hi(p.z), w, a[5]);
    a[6] = fmaf(bf_lo(p.w), w, a[6]);
    a[7] = fmaf(bf_hi(p.w), w, a[7]);
}

template <int D, bool RELU, bool OUTBF>
__global__ __launch_bounds__(256) void aggregate_sliced(const u16* __restrict__ x,
                                                        const int* __restrict__ row_ptr,
                                                        const long long* __restrict__ edata,
                                                        const float* __restrict__ dinv,
                                                        const float* __restrict__ bias,
                                                        void* __restrict__ outp, int n_nodes) {
    constexpr int NCH = D / 32;      // chunks: 8 (D=256) or 4 (D=128)
    constexpr int NSUB = 8 / NCH;    // node sub-tiles per bid-octet

    const int slot  = blockIdx.x & 7;
    const int chunk = slot & (NCH - 1);
    const int sub   = slot / NCH;            // 0 (D=256); 0..1 (D=128)
    const int wv    = threadIdx.x >> 6;
    const int lane  = threadIdx.x & 63;
    const int grp   = lane >> 2;             // node group 0..15
    const int l     = lane & 3;              // 16B (8 cols) within chunk row
    const int tile  = (int)(blockIdx.x >> 3);

    const int node  = tile * (64 * NSUB) + sub * 64 + wv * 16 + grp;
    const bool valid = node < n_nodes;
    const int naddr = valid ? node : 0;

    const u16* __restrict__ xc = x + (size_t)chunk * (size_t)n_nodes * 32;

    // per-lane bias (8 cols), uniform across groups
    float bv[8];
    {
        float4 ba = *(const float4*)(bias + chunk * 32 + l * 8);
        float4 bb = *(const float4*)(bias + chunk * 32 + l * 8 + 4);
        bv[0] = ba.x; bv[1] = ba.y; bv[2] = ba.z; bv[3] = ba.w;
        bv[4] = bb.x; bv[5] = bb.y; bv[6] = bb.z; bv[7] = bb.w;
    }

    const float di = dinv[naddr];
    int e  = valid ? row_ptr[node]     : 0;
    const int e1 = valid ? row_ptr[node + 1] : 0;

    float a0[8], a1[8];
    {
        // self loop
        uint4 ps = *(const uint4*)(xc + (size_t)naddr * 32 + l * 8);
        float w = valid ? di * di : 0.0f;
        a0[0] = bf_lo(ps.x) * w; a0[1] = bf_hi(ps.x) * w;
        a0[2] = bf_lo(ps.y) * w; a0[3] = bf_hi(ps.y) * w;
        a0[4] = bf_lo(ps.z) * w; a0[5] = bf_hi(ps.z) * w;
        a0[6] = bf_lo(ps.w) * w; a0[7] = bf_hi(ps.w) * w;
        #pragma unroll
        for (int j = 0; j < 8; ++j) a1[j] = 0.0f;
    }

    while (__any(e < e1)) {
        if (e < e1) {
            long long q = __builtin_nontemporal_load(&edata[e]);
            uint4 p = *(const uint4*)(xc + (size_t)(int)q * 32 + l * 8);
            upd8(a0, p, __int_as_float((int)(q >> 32)));
        }
        if (e + 1 < e1) {
            long long q = __builtin_nontemporal_load(&edata[e + 1]);
            uint4 p = *(const uint4*)(xc + (size_t)(int)q * 32 + l * 8);
            upd8(a1, p, __int_as_float((int)(q >> 32)));
        }
        e += 2;
    }

    if (valid) {
        float v[8];
        #pragma unroll
        for (int j = 0; j < 8; ++j) {
            float s = a0[j] + a1[j] + bv[j];
            v[j] = RELU ? fmaxf(s, 0.0f) : s;
        }
        if constexpr (OUTBF) {
            // chunk-major bf16 out (feeds gemm2 / next agg)
            u16* op = (u16*)outp + (size_t)chunk * (size_t)n_nodes * 32
                                  + (size_t)node * 32 + l * 8;
            uint4 pk;
            pk.x = (uint32)f2bf_rne(v[0]) | ((uint32)f2bf_rne(v[1]) << 16);
            pk.y = (uint32)f2bf_rne(v[2]) | ((uint32)f2bf_rne(v[3]) << 16);
            pk.z = (uint32)f2bf_rne(v[4]) | ((uint32)f2bf_rne(v[5]) << 16);
            pk.w = (uint32)f2bf_rne(v[6]) | ((uint32)f2bf_rne(v[7]) << 16);
            *(uint4*)op = pk;
        } else {
            // final output: row-major f32
            float* op = (float*)outp + (size_t)node * D + chunk * 32 + l * 8;
            *(float4*)op  = make_float4(v[0], v[1], v[2], v[3]);
            *(float4*)(op + 4) = make_float4(v[4], v[5], v[6], v[7]);
        }
    }
}

// ---------------- launcher ----------------

extern "C" void kernel_launch(void* const* d_in, const int* in_sizes, int n_in,
                              void* d_out, int out_size, void* d_ws, size_t ws_size,
                              hipStream_t stream) {
    const float* z  = (const float*)d_in[0];
    const int*   ei = (const int*)d_in[1];
    const float* W1 = (const float*)d_in[2];
    const float* b1 = (const float*)d_in[3];
    const float* W2 = (const float*)d_in[4];
    const float* b2 = (const float*)d_in[5];
    float* out = (float*)d_out;

    const int Nn = N_NODES, E = N_EDGES;
    const int* srcp = ei;
    const int* dstp = ei + E;

    char* ws = (char*)d_ws;
    size_t off = 0;
    auto alloc = [&](size_t bytes) -> char* {
        char* p = ws + off;
        off += (bytes + 511) & ~(size_t)511;
        return p;
    };
    u16*   zb     = (u16*)  alloc((size_t)Nn * D_IN * 2);
    u16*   w1t    = (u16*)  alloc((size_t)D_IN * D_HID * 2);
    u16*   w2t    = (u16*)  alloc((size_t)D_HID * D_OUT * 2);
    u16*   x1b    = (u16*)  alloc((size_t)Nn * D_HID * 2);   // chunk-major
    u16*   hb     = (u16*)  alloc((size_t)Nn * D_HID * 2);   // chunk-major
    u16*   h2b    = (u16*)  alloc((size_t)Nn * D_OUT * 2);   // chunk-major
    int*   cnt    = (int*)  alloc((size_t)Nn * 4);
    float* dinv   = (float*)alloc((size_t)Nn * 4);
    int*   row_ptr= (int*)  alloc((size_t)(Nn + 1) * 4);
    int*   rank   = (int*)  alloc((size_t)E * 4);
    int2*  edata  = (int2*) alloc((size_t)E * 8);

    hipMemsetAsync(cnt, 0, (size_t)Nn * 4, stream);
    prep_kernel<<<1024, 256, 0, stream>>>(z, dstp, W1, W2, zb, w1t, w2t, cnt, rank);
    scan_kernel<<<1, 1024, 0, stream>>>(cnt, dinv, row_ptr, Nn);
    fill_kernel<<<(E + 255) / 256, 256, 0, stream>>>(srcp, dstp, rank, row_ptr, dinv, edata, E);
    {
        dim3 grid((Nn + 127) / 128, D_HID / 128);
        gemm_bf16_kernel<D_HID, false><<<grid, 256, 0, stream>>>(zb, w1t, x1b, Nn);
    }
    {
        int blocks = ((Nn + 63) / 64) * 8;              // 6256: chunk = bid%8
        aggregate_sliced<D_HID, true, true><<<blocks, 256, 0, stream>>>(
            x1b, row_ptr, (const long long*)edata, dinv, b1, hb, Nn);
    }
    {
        dim3 grid((Nn + 127) / 128, D_OUT / 128);
        gemm_bf16_kernel<D_OUT, true><<<grid, 256, 0, stream>>>(hb, w2t, h2b, Nn);
    }
    {
        int blocks = ((Nn + 127) / 128) * 8;            // 3128: 4 chunks x 2 subtiles
        aggregate_sliced<D_OUT, false, false><<<blocks, 256, 0, stream>>>(
            h2b, row_ptr, (const long long*)edata, dinv, b2, out, Nn);
    }
}

// Round 5
// 318.905 us; speedup vs baseline: 1.4195x; 1.4195x over previous
//
#include <hip/hip_runtime.h>

// ---------------------------------------------------------------------------
// 2-layer GCN on MI355X.
//   h   = relu( Dinv (A+I) Dinv (z @ W1) + b1 )
//   out =       Dinv (A+I) Dinv (h @ W2) + b2
// R14: XCD column-sliced aggregation + tile-interleaved ELL edges.
// Evidence ledger: R12 proved chunk-major 32-col slices + blockIdx%8 make
// x-gathers L2-resident (FETCH 188->57MB) but butterfly epilogue serialized
// it (164us). R13 proved group-per-node lane-local gathering removes that,
// but its per-group 8B nontemporal edata reads amplified L2-miss traffic
// 57->297MB (64B line per 8B used, evict-first) -> miss-BW bound at 164us.
// R14 keeps both wins and fixes edata: edges stored ELL-interleaved per
// aligned 16-node tile (50000 = 3125 x 16 exactly): entry(node 16t+g, rank r)
// at base[t] + r*16 + g, padded to tile width W_t with (col0,w=0) no-ops.
// A wave reads 16 groups x 8B = 128B contiguous, fully consumed -> nt safe.
// x-gather: 4 lanes x 16B = full 64B row from the L2-resident slice.
// No shfl, no divergence (uniform W_t iterations), unroll-4 MLP.
// 9 dispatches: memset, prep, scan, fill, pad, gemm1, agg1, gemm2, agg2.
// ---------------------------------------------------------------------------

#define N_NODES 50000
#define N_EDGES 800000
#define D_IN    256
#define D_HID   256
#define D_OUT   128
#define N_TILES 3125            // N_NODES / 16, exact
#define ELL_CAP (N_TILES * 64 * 16)   // width cap 64 (max deg Poisson(16): P>64 ~ 1e-18)

typedef unsigned int uint32;
typedef unsigned short u16;

typedef __attribute__((ext_vector_type(8))) short bf16x8;   // MFMA A/B frag
typedef __attribute__((ext_vector_type(4))) float f32x4;    // MFMA C/D frag

__device__ __forceinline__ u16 f2bf_rne(float f) {
    union { float f; uint32 u; } c; c.f = f;
    uint32 u = c.u;
    u += 0x7FFFu + ((u >> 16) & 1u);
    return (u16)(u >> 16);
}
__device__ __forceinline__ float bf_lo(uint32 p) {
    union { uint32 u; float f; } c; c.u = p << 16; return c.f;
}
__device__ __forceinline__ float bf_hi(uint32 p) {
    union { uint32 u; float f; } c; c.u = p & 0xFFFF0000u; return c.f;
}

// ---------------- fused independent prep ----------------
// z->bf16, W1^T bf16, W2^T bf16, degree atomics WITH rank capture.

__global__ __launch_bounds__(256) void prep_kernel(const float* __restrict__ z,
                                                   const int* __restrict__ dst,
                                                   const float* __restrict__ W1,
                                                   const float* __restrict__ W2,
                                                   u16* __restrict__ zb,
                                                   u16* __restrict__ w1t,
                                                   u16* __restrict__ w2t,
                                                   int* __restrict__ cnt,
                                                   int* __restrict__ rank) {
    const int g = blockIdx.x * 256 + threadIdx.x;
    const int GT = gridDim.x * 256;

    for (int c = g; c < N_NODES * D_IN / 8; c += GT) {
        int i = c * 8;
        float4 a = *(const float4*)(z + i);
        float4 d = *(const float4*)(z + i + 4);
        uint4 pk;
        pk.x = (uint32)f2bf_rne(a.x) | ((uint32)f2bf_rne(a.y) << 16);
        pk.y = (uint32)f2bf_rne(a.z) | ((uint32)f2bf_rne(a.w) << 16);
        pk.z = (uint32)f2bf_rne(d.x) | ((uint32)f2bf_rne(d.y) << 16);
        pk.w = (uint32)f2bf_rne(d.z) | ((uint32)f2bf_rne(d.w) << 16);
        *(uint4*)(zb + i) = pk;
    }
    for (int idx = g; idx < D_IN * D_HID + D_HID * D_OUT; idx += GT) {
        if (idx < D_IN * D_HID) {
            int nrow = idx >> 8, kcol = idx & 255;
            w1t[idx] = f2bf_rne(W1[kcol * D_HID + nrow]);
        } else {
            int j = idx - D_IN * D_HID;
            int nrow = j >> 8, kcol = j & 255;
            w2t[j] = f2bf_rne(W2[kcol * D_OUT + nrow]);
        }
    }
    for (int i = g; i < N_EDGES; i += GT)
        rank[i] = atomicAdd(&cnt[dst[i]], 1);
}

// ---------------- single-block scan: per-tile ELL width + base -------------
// 1024 threads x 4 rounds over 3125 tiles. Per tile: W_t = max of 16 degrees
// (dinv computed alongside); tile_base = 16 * exclusive_prefix(W).

__global__ __launch_bounds__(1024) void scan_kernel(const int* __restrict__ cnt,
                                                    float* __restrict__ dinv,
                                                    int* __restrict__ tile_base) {
    __shared__ int wtot[16];
    __shared__ int carry_s;
    const int t = threadIdx.x;
    const int lane = t & 63, w = t >> 6;
    if (t == 0) carry_s = 0;
    __syncthreads();

    for (int base = 0; base < N_TILES; base += 1024) {
        int tile = base + t;
        int wd = 0;
        int4 c0, c1, c2, c3;
        if (tile < N_TILES) {
            const int4* cp = (const int4*)(cnt + tile * 16);
            c0 = cp[0]; c1 = cp[1]; c2 = cp[2]; c3 = cp[3];
            int m0 = max(max(c0.x, c0.y), max(c0.z, c0.w));
            int m1 = max(max(c1.x, c1.y), max(c1.z, c1.w));
            int m2 = max(max(c2.x, c2.y), max(c2.z, c2.w));
            int m3 = max(max(c3.x, c3.y), max(c3.z, c3.w));
            wd = max(max(m0, m1), max(m2, m3));

            float4* dv = (float4*)(dinv + tile * 16);
            dv[0] = make_float4(rsqrtf((float)(c0.x + 1)), rsqrtf((float)(c0.y + 1)),
                                rsqrtf((float)(c0.z + 1)), rsqrtf((float)(c0.w + 1)));
            dv[1] = make_float4(rsqrtf((float)(c1.x + 1)), rsqrtf((float)(c1.y + 1)),
                                rsqrtf((float)(c1.z + 1)), rsqrtf((float)(c1.w + 1)));
            dv[2] = make_float4(rsqrtf((float)(c2.x + 1)), rsqrtf((float)(c2.y + 1)),
                                rsqrtf((float)(c2.z + 1)), rsqrtf((float)(c2.w + 1)));
            dv[3] = make_float4(rsqrtf((float)(c3.x + 1)), rsqrtf((float)(c3.y + 1)),
                                rsqrtf((float)(c3.z + 1)), rsqrtf((float)(c3.w + 1)));
        }
        int x = wd;
        #pragma unroll
        for (int off = 1; off < 64; off <<= 1) {
            int u = __shfl_up(x, off, 64);
            if (lane >= off) x += u;
        }
        if (lane == 63) wtot[w] = x;
        __syncthreads();

        int wbase = 0;
        #pragma unroll
        for (int j = 0; j < 16; ++j) if (j < w) wbase += wtot[j];
        int excl = carry_s + wbase + x - wd;
        if (tile < N_TILES) tile_base[tile] = excl * 16;
        __syncthreads();
        if (t == 0) {
            int tot = 0;
            #pragma unroll
            for (int j = 0; j < 16; ++j) tot += wtot[j];
            carry_s += tot;
        }
        __syncthreads();
    }
    if (t == 0) tile_base[N_TILES] = carry_s * 16;
}

// ---------------- atomic-free ELL fill: packed (col, weight) ---------------

__global__ void fill_kernel(const int* __restrict__ src, const int* __restrict__ dst,
                            const int* __restrict__ rank, const int* __restrict__ tile_base,
                            const float* __restrict__ dinv,
                            int2* __restrict__ edata, int n_edges) {
    int i = blockIdx.x * blockDim.x + threadIdx.x;
    if (i < n_edges) {
        int s = src[i], d = dst[i];
        float w = dinv[s] * dinv[d];
        edata[tile_base[d >> 4] + rank[i] * 16 + (d & 15)] = make_int2(s, __float_as_int(w));
    }
}

// ---------------- pad: zero the ELL slots with r >= deg --------------------
// (col=0, w=+0.0) -> gather of row 0 with weight 0: exact no-op.

__global__ __launch_bounds__(256) void pad_kernel(const int* __restrict__ cnt,
                                                  const int* __restrict__ tile_base,
                                                  int2* __restrict__ edata) {
    const int tile = blockIdx.x;
    const int base = tile_base[tile];
    const int slots = tile_base[tile + 1] - base;   // W_t * 16
    for (int idx = threadIdx.x; idx < slots; idx += 256) {
        int g = idx & 15, r = idx >> 4;
        if (r >= cnt[tile * 16 + g]) edata[base + idx] = make_int2(0, 0);
    }
}

// ---------------- bf16 MFMA GEMM (C chunk-major; A row- or chunk-major) ----

template <int NT, bool ACH>
__global__ __launch_bounds__(256, 4) void gemm_bf16_kernel(const u16* __restrict__ A,
                                                           const u16* __restrict__ BT,
                                                           u16* __restrict__ C, int M) {
    const int K = 256;
    __shared__ short As[128 * 32];
    __shared__ short Bs[128 * 32];

    const int m0 = blockIdx.x * 128;
    const int n0 = blockIdx.y * 128;
    const int t  = threadIdx.x;
    const int w  = t >> 6;
    const int lane = t & 63;
    const int lm = lane & 15;
    const int lq = lane >> 4;
    const int wm = w & 1;
    const int wn = w >> 1;

    f32x4 acc[4][4] = {};

    for (int k0 = 0; k0 < K; k0 += 32) {
        #pragma unroll
        for (int j = 0; j < 2; ++j) {
            int c = w * 128 + j * 64 + lane;
            int row = c >> 2;
            int kc = k0 + (c & 3) * 8;
            int gm = m0 + row; if (gm >= M) gm = M - 1;
            const u16* gpa;
            if constexpr (ACH)
                gpa = A + (size_t)(kc >> 5) * (size_t)M * 32 + (size_t)gm * 32 + (kc & 31);
            else
                gpa = A + (size_t)gm * K + kc;
            const u16* gpb = BT + (size_t)(n0 + row) * K + kc;
            __builtin_amdgcn_global_load_lds(
                (const __attribute__((address_space(1))) void*)gpa,
                (__attribute__((address_space(3))) void*)(As + (w * 128 + j * 64) * 8),
                16, 0, 0);
            __builtin_amdgcn_global_load_lds(
                (const __attribute__((address_space(1))) void*)gpb,
                (__attribute__((address_space(3))) void*)(Bs + (w * 128 + j * 64) * 8),
                16, 0, 0);
        }
        __syncthreads();

        bf16x8 af[4], bf[4];
        #pragma unroll
        for (int mt = 0; mt < 4; ++mt)
            af[mt] = *(const bf16x8*)&As[(wm * 64 + mt * 16 + lm) * 32 + lq * 8];
        #pragma unroll
        for (int nt = 0; nt < 4; ++nt)
            bf[nt] = *(const bf16x8*)&Bs[(wn * 64 + nt * 16 + lm) * 32 + lq * 8];

        #pragma unroll
        for (int mt = 0; mt < 4; ++mt)
            #pragma unroll
            for (int nt = 0; nt < 4; ++nt)
                acc[mt][nt] = __builtin_amdgcn_mfma_f32_16x16x32_bf16(
                    af[mt], bf[nt], acc[mt][nt], 0, 0, 0);

        __syncthreads();
    }

    // C write: chunk-major [gn>>5][gm][gn&31]
    #pragma unroll
    for (int mt = 0; mt < 4; ++mt) {
        #pragma unroll
        for (int r = 0; r < 4; ++r) {
            int gm = m0 + wm * 64 + mt * 16 + lq * 4 + r;
            if (gm < M) {
                #pragma unroll
                for (int nt = 0; nt < 4; ++nt) {
                    int gn = n0 + wn * 64 + nt * 16 + lm;
                    C[(size_t)(gn >> 5) * (size_t)M * 32 + (size_t)gm * 32 + (gn & 31)]
                        = f2bf_rne(acc[mt][nt][r]);
                }
            }
        }
    }
}

// ---------------- XCD column-sliced aggregation over ELL tiles -------------
// chunk = blockIdx%8 (mod NCH): each XCD streams one 32-col chunk slice
// (L2-resident, verified R12). One wave = 16 groups x 4 lanes; group g owns
// node tile*16+g; ELL interleave makes the wave's edata read 128B contiguous
// (fully consumed -> nt safe); x-gather is 4 lanes x 16B = full 64B row.
// All groups iterate the uniform tile width; pad entries are FMA-with-0.

__device__ __forceinline__ void upd8(float* a, uint4 p, float w) {
    a[0] = fmaf(bf_lo(p.x), w, a[0]);
    a[1] = fmaf(bf_hi(p.x), w, a[1]);
    a[2] = fmaf(bf_lo(p.y), w, a[2]);
    a[3] = fmaf(bf_hi(p.y), w, a[3]);
    a[4] = fmaf(bf_lo(p.z), w, a[4]);
    a[5] = fmaf(bf_hi(p.z), w, a[5]);
    a[6] = fmaf(bf_lo(p.w), w, a[6]);
    a[7] = fmaf(bf_hi(p.w), w, a[7]);
}

template <int D, bool RELU, bool OUTBF>
__global__ __launch_bounds__(256) void aggregate_ell(const u16* __restrict__ x,
                                                     const int* __restrict__ tile_base,
                                                     const long long* __restrict__ edata,
                                                     const float* __restrict__ dinv,
                                                     const float* __restrict__ bias,
                                                     void* __restrict__ outp, int n_nodes) {
    constexpr int NCH = D / 32;      // chunks: 8 (D=256) or 4 (D=128)
    constexpr int NSUB = 8 / NCH;    // tile sub-ranges per bid-octet

    const int slot  = blockIdx.x & 7;
    const int chunk = slot & (NCH - 1);
    const int sub   = slot / NCH;            // 0 (D=256); 0..1 (D=128)
    const int wv    = threadIdx.x >> 6;
    const int lane  = threadIdx.x & 63;
    const int grp   = lane >> 2;             // node group 0..15
    const int l     = lane & 3;              // 16B (8 cols) within chunk row

    const int tile = (int)(blockIdx.x >> 3) * (4 * NSUB) + sub * 4 + wv;
    if (tile >= N_TILES) return;             // wave-uniform
    const int node = tile * 16 + grp;        // always < n_nodes (3125*16 exact)

    const u16* __restrict__ xc = x + (size_t)chunk * (size_t)n_nodes * 32;

    // per-lane bias (8 cols), uniform across groups
    float bv[8];
    {
        float4 ba = *(const float4*)(bias + chunk * 32 + l * 8);
        float4 bb = *(const float4*)(bias + chunk * 32 + l * 8 + 4);
        bv[0] = ba.x; bv[1] = ba.y; bv[2] = ba.z; bv[3] = ba.w;
        bv[4] = bb.x; bv[5] = bb.y; bv[6] = bb.z; bv[7] = bb.w;
    }

    const int base = tile_base[tile];
    const int W = (tile_base[tile + 1] - base) >> 4;
    const long long* __restrict__ ep = edata + base + grp;

    float a0[8], a1[8];
    {
        // self loop
        const float di = dinv[node];
        uint4 ps = *(const uint4*)(xc + (size_t)node * 32 + l * 8);
        float w = di * di;
        a0[0] = bf_lo(ps.x) * w; a0[1] = bf_hi(ps.x) * w;
        a0[2] = bf_lo(ps.y) * w; a0[3] = bf_hi(ps.y) * w;
        a0[4] = bf_lo(ps.z) * w; a0[5] = bf_hi(ps.z) * w;
        a0[6] = bf_lo(ps.w) * w; a0[7] = bf_hi(ps.w) * w;
        #pragma unroll
        for (int j = 0; j < 8; ++j) a1[j] = 0.0f;
    }

    int r = 0;
    for (; r + 4 <= W; r += 4) {
        long long q0 = __builtin_nontemporal_load(ep + (r + 0) * 16);
        long long q1 = __builtin_nontemporal_load(ep + (r + 1) * 16);
        long long q2 = __builtin_nontemporal_load(ep + (r + 2) * 16);
        long long q3 = __builtin_nontemporal_load(ep + (r + 3) * 16);
        uint4 p0 = *(const uint4*)(xc + (size_t)(int)q0 * 32 + l * 8);
        uint4 p1 = *(const uint4*)(xc + (size_t)(int)q1 * 32 + l * 8);
        uint4 p2 = *(const uint4*)(xc + (size_t)(int)q2 * 32 + l * 8);
        uint4 p3 = *(const uint4*)(xc + (size_t)(int)q3 * 32 + l * 8);
        upd8(a0, p0, __int_as_float((int)(q0 >> 32)));
        upd8(a1, p1, __int_as_float((int)(q1 >> 32)));
        upd8(a0, p2, __int_as_float((int)(q2 >> 32)));
        upd8(a1, p3, __int_as_float((int)(q3 >> 32)));
    }
    for (; r < W; ++r) {
        long long q = __builtin_nontemporal_load(ep + r * 16);
        uint4 p = *(const uint4*)(xc + (size_t)(int)q * 32 + l * 8);
        upd8(a0, p, __int_as_float((int)(q >> 32)));
    }

    float v[8];
    #pragma unroll
    for (int j = 0; j < 8; ++j) {
        float s = a0[j] + a1[j] + bv[j];
        v[j] = RELU ? fmaxf(s, 0.0f) : s;
    }
    if constexpr (OUTBF) {
        // chunk-major bf16 out (feeds gemm2 / next agg)
        u16* op = (u16*)outp + (size_t)chunk * (size_t)n_nodes * 32
                              + (size_t)node * 32 + l * 8;
        uint4 pk;
        pk.x = (uint32)f2bf_rne(v[0]) | ((uint32)f2bf_rne(v[1]) << 16);
        pk.y = (uint32)f2bf_rne(v[2]) | ((uint32)f2bf_rne(v[3]) << 16);
        pk.z = (uint32)f2bf_rne(v[4]) | ((uint32)f2bf_rne(v[5]) << 16);
        pk.w = (uint32)f2bf_rne(v[6]) | ((uint32)f2bf_rne(v[7]) << 16);
        *(uint4*)op = pk;
    } else {
        // final output: row-major f32
        float* op = (float*)outp + (size_t)node * D + chunk * 32 + l * 8;
        *(float4*)op  = make_float4(v[0], v[1], v[2], v[3]);
        *(float4*)(op + 4) = make_float4(v[4], v[5], v[6], v[7]);
    }
}

// ---------------- launcher ----------------

extern "C" void kernel_launch(void* const* d_in, const int* in_sizes, int n_in,
                              void* d_out, int out_size, void* d_ws, size_t ws_size,
                              hipStream_t stream) {
    const float* z  = (const float*)d_in[0];
    const int*   ei = (const int*)d_in[1];
    const float* W1 = (const float*)d_in[2];
    const float* b1 = (const float*)d_in[3];
    const float* W2 = (const float*)d_in[4];
    const float* b2 = (const float*)d_in[5];
    float* out = (float*)d_out;

    const int Nn = N_NODES, E = N_EDGES;
    const int* srcp = ei;
    const int* dstp = ei + E;

    char* ws = (char*)d_ws;
    size_t off = 0;
    auto alloc = [&](size_t bytes) -> char* {
        char* p = ws + off;
        off += (bytes + 511) & ~(size_t)511;
        return p;
    };
    u16*   zb     = (u16*)  alloc((size_t)Nn * D_IN * 2);
    u16*   w1t    = (u16*)  alloc((size_t)D_IN * D_HID * 2);
    u16*   w2t    = (u16*)  alloc((size_t)D_HID * D_OUT * 2);
    u16*   x1b    = (u16*)  alloc((size_t)Nn * D_HID * 2);   // chunk-major
    u16*   hb     = (u16*)  alloc((size_t)Nn * D_HID * 2);   // chunk-major
    u16*   h2b    = (u16*)  alloc((size_t)Nn * D_OUT * 2);   // chunk-major
    int*   cnt    = (int*)  alloc((size_t)Nn * 4);
    float* dinv   = (float*)alloc((size_t)Nn * 4);
    int*   tbase  = (int*)  alloc((size_t)(N_TILES + 1) * 4);
    int*   rank   = (int*)  alloc((size_t)E * 4);
    int2*  edata  = (int2*) alloc((size_t)ELL_CAP * 8);

    hipMemsetAsync(cnt, 0, (size_t)Nn * 4, stream);
    prep_kernel<<<1024, 256, 0, stream>>>(z, dstp, W1, W2, zb, w1t, w2t, cnt, rank);
    scan_kernel<<<1, 1024, 0, stream>>>(cnt, dinv, tbase);
    fill_kernel<<<(E + 255) / 256, 256, 0, stream>>>(srcp, dstp, rank, tbase, dinv, edata, E);
    pad_kernel<<<N_TILES, 256, 0, stream>>>(cnt, tbase, edata);
    {
        dim3 grid((Nn + 127) / 128, D_HID / 128);
        gemm_bf16_kernel<D_HID, false><<<grid, 256, 0, stream>>>(zb, w1t, x1b, Nn);
    }
    {
        int blocks = ((N_TILES + 3) / 4) * 8;           // 6256: chunk = bid%8
        aggregate_ell<D_HID, true, true><<<blocks, 256, 0, stream>>>(
            x1b, tbase, (const long long*)edata, dinv, b1, hb, Nn);
    }
    {
        dim3 grid((Nn + 127) / 128, D_OUT / 128);
        gemm_bf16_kernel<D_OUT, true><<<grid, 256, 0, stream>>>(hb, w2t, h2b, Nn);
    }
    {
        int blocks = ((N_TILES + 7) / 8) * 8;           // 3128: 4 chunks x 2 subtiles
        aggregate_ell<D_OUT, false, false><<<blocks, 256, 0, stream>>>(
            h2b, tbase, (const long long*)edata, dinv, b2, out, Nn);
    }
}